// Round 22
// baseline (143.532 us; speedup 1.0000x reference)
//
#include <hip/hip_runtime.h>
#include <hip/hip_bf16.h>
#include <cstdint>

#define B_ 4
#define N_ 2048
#define D_ 512
#define E_ 512
#define H_ 8
#define CH_ 64
#define M_ (B_*N_)   // 8192

typedef __attribute__((ext_vector_type(8))) short bf16x8;
typedef __attribute__((ext_vector_type(4))) float f32x4;
typedef __attribute__((ext_vector_type(16))) float f32x16;
using u16 = unsigned short;
using u32 = unsigned int;

__device__ __forceinline__ u16 f2bf(float f) {
  union { __hip_bfloat16 h; u16 u; } cv;
  cv.h = __float2bfloat16(f);
  return cv.u;
}

__device__ __forceinline__ float fexp2(float x) {
#if __has_builtin(__builtin_amdgcn_exp2f)
  return __builtin_amdgcn_exp2f(x);
#else
  return exp2f(x);
#endif
}

__device__ __forceinline__ void async16(const void* g, void* l) {
  __builtin_amdgcn_global_load_lds(
      (__attribute__((address_space(1))) void*)(g),
      (__attribute__((address_space(3))) void*)(l),
      16, 0, 0);
}

// ---------------- prepass: W^T only (f32 -> bf16 transpose, 1.5MB) ----------------
__global__ void prep_w(const float* __restrict__ Wq, const float* __restrict__ Wk,
                       const float* __restrict__ Wv,
                       u16* __restrict__ tq, u16* __restrict__ tk, u16* __restrict__ tv) {
  int bid = blockIdx.x;
  int t = bid >> 10;                       // 1024 blocks per matrix
  const float* W = (t == 0) ? Wq : (t == 1 ? Wk : Wv);
  u16* T = (t == 0) ? tq : (t == 1 ? tk : tv);
  int idx = ((bid & 1023) << 8) + threadIdx.x;
  int e = idx >> 9, kd = idx & 511;
  T[idx] = f2bf(W[kd * E_ + e]);
}

// ---------------- projection GEMM v5: A direct-from-global (no LDS for A) ----------------
// X: f32 [M_][D_]. WT: bf16 [E_][D_]. A-tile elements have reuse=2 (wc pair) and are
// L2-resident via XCD-owner decode -> skip LDS: each lane loads its fragment's 32B
// (2 x float4) directly and converts. Barrier now guards only B's 2 async16.
#define GBM 128
#define GBN 64
#define GBK 64

__global__ __launch_bounds__(256) void proj_gemm(
    const float* __restrict__ xq, const float* __restrict__ xk, const float* __restrict__ xv,
    const u16* __restrict__ wtq, const u16* __restrict__ wtk, const u16* __restrict__ wtv,
    const float* __restrict__ bq, const float* __restrict__ bk, const float* __restrict__ bv,
    u16* __restrict__ Qp, u16* __restrict__ Kp, u16* __restrict__ Vp) {
  const int bid = blockIdx.x;
  const int xcd = bid & 7;
  const int t   = bid >> 3;
  const int x8  = t & 7;
  const int gp  = xcd * 24 + (t >> 3);
  const int y   = gp & 63;
  const int z   = gp >> 6;

  const float* X = (z == 0) ? xq : (z == 1 ? xk : xv);
  const u16* WT  = (z == 0) ? wtq : (z == 1 ? wtk : wtv);
  const float* bias = (z == 0) ? bq : (z == 1 ? bk : bv);
  u16* Out = (z == 0) ? Qp : (z == 1 ? Kp : Vp);
  const float scale = (z == 0) ? 0.18033688011112042f : 1.0f;  // 0.125*log2(e)
  const bool vlayout = (z == 2);

  __shared__ __align__(16) u16 Bs[GBN * GBK];   // 8KB (B only)

  const int tid = threadIdx.x;
  const int l = tid & 63, w = tid >> 6;
  const int wr = w >> 1, wc = w & 1;
  const int m0 = y * GBM;
  const int e0 = x8 * GBN;

  f32x4 acc[4][2] = {};

  // per-lane A addressing: row = m0 + wr*64 + m*16 + (l&15); col base (l>>4)*8
  const float* arow_base[4];
#pragma unroll
  for (int m = 0; m < 4; ++m)
    arow_base[m] = X + (size_t)(m0 + wr * 64 + m * 16 + (l & 15)) * D_ + ((l >> 4) << 3);

  for (int ks = 0; ks < D_ / GBK; ++ks) {
    const int k0 = ks * GBK;
    // B: async16 direct to LDS (bf16 W^T, 8KB = 2 chunks)
#pragma unroll
    for (int i = 0; i < 2; ++i) {
      int o = i * 4096 + tid * 16;
      int row = o >> 7, colb = o & 127;
      int scol = colb ^ ((row & 7) << 4);
      async16((const char*)WT + ((size_t)(e0 + row) * D_ + k0) * 2 + scol, (char*)Bs + o);
    }
    // A: direct f32 loads for all 8 fragments (issued before the barrier; no LDS)
    float4 alo[4][2], ahi[4][2];
#pragma unroll
    for (int m = 0; m < 4; ++m)
#pragma unroll
      for (int kk = 0; kk < 2; ++kk) {
        const float* src = arow_base[m] + k0 + kk * 32;
        alo[m][kk] = *reinterpret_cast<const float4*>(src);
        ahi[m][kk] = *reinterpret_cast<const float4*>(src + 4);
      }
    __syncthreads();   // B staged (drains vmcnt incl. A loads)
#pragma unroll
    for (int kk = 0; kk < 2; ++kk) {
      bf16x8 bfr[2];
#pragma unroll
      for (int n = 0; n < 2; ++n) {
        int row = wc * 32 + n * 16 + (l & 15);
        int addr = (row << 7) + kk * 64 + ((l >> 4) << 4);
        addr ^= (row & 7) << 4;
        bfr[n] = *reinterpret_cast<const bf16x8*>((const char*)Bs + addr);
      }
#pragma unroll
      for (int m = 0; m < 4; ++m) {
        union { u16 us[8]; bf16x8 v8; } cu;
        cu.us[0] = f2bf(alo[m][kk].x); cu.us[1] = f2bf(alo[m][kk].y);
        cu.us[2] = f2bf(alo[m][kk].z); cu.us[3] = f2bf(alo[m][kk].w);
        cu.us[4] = f2bf(ahi[m][kk].x); cu.us[5] = f2bf(ahi[m][kk].y);
        cu.us[6] = f2bf(ahi[m][kk].z); cu.us[7] = f2bf(ahi[m][kk].w);
#pragma unroll
        for (int n = 0; n < 2; ++n)
          acc[m][n] = __builtin_amdgcn_mfma_f32_16x16x32_bf16(cu.v8, bfr[n], acc[m][n], 0, 0, 0);
      }
    }
    __syncthreads();   // protect Bs reuse
  }

#pragma unroll
  for (int m = 0; m < 4; ++m) {
#pragma unroll
    for (int n = 0; n < 2; ++n) {
      int ge = e0 + wc * 32 + n * 16 + (l & 15);
      int h = ge >> 6, c = ge & 63;
      float bv_ = bias[ge];
      int gm0 = m0 + wr * 64 + m * 16 + ((l >> 4) << 2);
      int b = gm0 >> 11, nn0 = gm0 & 2047;
      if (vlayout) {
        short4 sv;
#pragma unroll
        for (int j = 0; j < 4; ++j)
          ((u16*)&sv)[j] = f2bf((acc[m][n][j] + bv_) * scale);
        int np = (((nn0 >> 2) ^ (nn0 >> 3)) & 1) ? (nn0 ^ 12) : nn0;
        *reinterpret_cast<short4*>(
            &Out[(((size_t)b * H_ + h) * CH_ + c) * N_ + np]) = sv;
      } else {
#pragma unroll
        for (int j = 0; j < 4; ++j) {
          u16 oval = f2bf((acc[m][n][j] + bv_) * scale);
          Out[((((size_t)b * H_ + h) * N_ + nn0 + j) << 6) + c] = oval;
        }
      }
    }
  }
}

// ---------------- flash attention v8 (frozen best: conflict-free pair-interleave, KVB=32) ----
#define QBLK 128
#define KVB 32
#define NTH 32   // tiles per half

#define MFMA32(A, Bv, C) __builtin_amdgcn_mfma_f32_32x32x16_bf16((A), (Bv), (C), 0, 0, 0)

__global__ __launch_bounds__(512, 2) void attn_kernel(
    const u16* __restrict__ Qp, const u16* __restrict__ Kp, const u16* __restrict__ Vp,
    float* __restrict__ out) {
  __shared__ __align__(16) u16 Kb[2][2][2048];   // [dbuf][half] 4KB tiles
  __shared__ __align__(16) u16 Vb[2][2][2048];
  __shared__ float shL[4][64];

  const int tid = threadIdx.x;
  const int l = tid & 63, w = tid >> 6;
  const int wsub = w & 3, hf = w >> 2;
  const int qcol = l & 31, hi = l >> 5;

  const int beta = blockIdx.x;
  const int xcd = beta & 7, r = beta >> 3;
  const int bh = xcd * 4 + (r >> 4);
  const int qt = r & 15;

  const u16* Qh = Qp + (size_t)bh * N_ * CH_;
  const u16* Kh = Kp + (size_t)bh * N_ * CH_;
  const u16* Vh = Vp + (size_t)bh * CH_ * N_;
  const int bb = bh >> 3, hh = bh & 7;
  const int qrow = qt * QBLK + wsub * 32 + qcol;

  bf16x8 qf[4];
  {
    const u16* qptr = Qh + (size_t)qrow * CH_;
#pragma unroll
    for (int ks = 0; ks < 4; ++ks)
      qf[ks] = *reinterpret_cast<const bf16x8*>(qptr + ks * 16 + hi * 8);
  }

  f32x16 o0 = {}, o1 = {};
  float lrun = 0.f;

  const int kbase = ((qcol >> 1) << 8) + ((qcol & 1) << 4);
  const int kxor  = (qcol >> 1) & 7;
  const int vbase = ((qcol >> 2) << 8) + ((qcol & 3) << 4);
  const int vxor  = (qcol >> 2) & 3;

  const int st = tid & 255;
  const int tb = hf * (N_ / 2);

  const int so    = st * 16;
  const int kpair = so >> 8;
  const int krow  = (kpair << 1) | ((so >> 4) & 1);
  const int kcol  = ((((so >> 5) & 7) ^ (kpair & 7)) << 4) | (so & 15);
  const int vquad = so >> 8;
  const int vrow  = (vquad << 2) | ((so >> 4) & 3);
  const int vcol  = ((((so >> 6) & 3) ^ (vquad & 3)) << 4) | (so & 15);

#define STAGE(BUF, KV) do {                                                      \
    async16((const char*)Kh + (size_t)((KV) + krow) * 128 + kcol,                \
            (char*)&Kb[BUF][hf][0] + so);                                        \
    async16((const char*)Vh + (size_t)vrow * (N_ * 2) + (KV) * 2 + vcol,         \
            (char*)&Vb[BUF][hf][0] + so);                                        \
  } while (0)

#define TILE(BUF, TL) do {                                                       \
    if ((TL) + 1 < NTH) STAGE((BUF) ^ 1, tb + ((TL) + 1) * KVB);                 \
    f32x16 s0 = {};                                                              \
    __builtin_amdgcn_s_setprio(1);                                               \
    _Pragma("unroll")                                                            \
    for (int ks = 0; ks < 4; ++ks) {                                             \
      int ka = kbase + ((((ks << 1) | hi) ^ kxor) << 5);                         \
      bf16x8 kf = *reinterpret_cast<const bf16x8*>((const char*)&Kb[BUF][hf][0] + ka); \
      s0 = MFMA32(kf, qf[ks], s0);                                               \
    }                                                                            \
    __builtin_amdgcn_s_setprio(0);                                               \
    _Pragma("unroll")                                                            \
    for (int rr = 0; rr < 16; ++rr) s0[rr] = fexp2(s0[rr]);                      \
    {                                                                            \
      float t0 = (s0[0] + s0[1]) + (s0[2] + s0[3]);                              \
      float t1 = (s0[4] + s0[5]) + (s0[6] + s0[7]);                              \
      float t2 = (s0[8] + s0[9]) + (s0[10] + s0[11]);                            \
      float t3 = (s0[12] + s0[13]) + (s0[14] + s0[15]);                          \
      float rsum = (t0 + t1) + (t2 + t3);                                        \
      rsum += __shfl_xor(rsum, 32);                                              \
      lrun += rsum;                                                              \
    }                                                                            \
    __builtin_amdgcn_s_setprio(1);                                               \
    _Pragma("unroll")                                                            \
    for (int ks = 0; ks < 2; ++ks) {                                             \
      union { u16 us[8]; bf16x8 v8; } pu;                                        \
      _Pragma("unroll")                                                          \
      for (int j = 0; j < 8; ++j) pu.us[j] = f2bf(s0[ks * 8 + j]);               \
      int va = vbase + ((((ks << 1) | hi) ^ vxor) << 6);                         \
      bf16x8 v0 = *reinterpret_cast<const bf16x8*>((const char*)&Vb[BUF][hf][0] + va);        \
      bf16x8 v1 = *reinterpret_cast<const bf16x8*>((const char*)&Vb[BUF][hf][0] + va + 2048); \
      o0 = MFMA32(v0, pu.v8, o0);                                                \
      o1 = MFMA32(v1, pu.v8, o1);                                                \
    }                                                                            \
    __builtin_amdgcn_s_setprio(0);                                               \
    __syncthreads();                                                             \
  } while (0)

  STAGE(0, tb);
  __syncthreads();

  for (int tl = 0; tl < NTH; tl += 2) {
    TILE(0, tl);
    TILE(1, tl + 1);
  }

  float* pb = (wsub < 2) ? ((float*)&Kb[0][0][0] + wsub * 2048 + l * 4)
                         : ((float*)&Vb[0][0][0] + (wsub - 2) * 2048 + l * 4);
  if (hf == 1) {
#pragma unroll
    for (int c = 0; c < 4; ++c) {
      float4 s;
      s.x = o0[c * 4 + 0]; s.y = o0[c * 4 + 1];
      s.z = o0[c * 4 + 2]; s.w = o0[c * 4 + 3];
      *reinterpret_cast<float4*>(pb + c * 256) = s;
    }
#pragma unroll
    for (int c = 0; c < 4; ++c) {
      float4 s;
      s.x = o1[c * 4 + 0]; s.y = o1[c * 4 + 1];
      s.z = o1[c * 4 + 2]; s.w = o1[c * 4 + 3];
      *reinterpret_cast<float4*>(pb + (4 + c) * 256) = s;
    }
    shL[wsub][l] = lrun;
  }
  __syncthreads();
  if (hf == 0) {
    float inv = 1.0f / (lrun + shL[wsub][l]);
    const size_t obase = ((size_t)bb * N_ + qrow) * E_ + hh * CH_;
#pragma unroll
    for (int c = 0; c < 4; ++c) {
      float4 p = *reinterpret_cast<const float4*>(pb + c * 256);
      float4 stv;
      stv.x = (o0[c * 4 + 0] + p.x) * inv;
      stv.y = (o0[c * 4 + 1] + p.y) * inv;
      stv.z = (o0[c * 4 + 2] + p.z) * inv;
      stv.w = (o0[c * 4 + 3] + p.w) * inv;
      *reinterpret_cast<float4*>(out + obase + c * 8 + hi * 4) = stv;
    }
#pragma unroll
    for (int c = 0; c < 4; ++c) {
      float4 p = *reinterpret_cast<const float4*>(pb + (4 + c) * 256);
      float4 stv;
      stv.x = (o1[c * 4 + 0] + p.x) * inv;
      stv.y = (o1[c * 4 + 1] + p.y) * inv;
      stv.z = (o1[c * 4 + 2] + p.z) * inv;
      stv.w = (o1[c * 4 + 3] + p.w) * inv;
      *reinterpret_cast<float4*>(out + obase + 32 + c * 8 + hi * 4) = stv;
    }
  }
#undef STAGE
#undef TILE
}

extern "C" void kernel_launch(void* const* d_in, const int* in_sizes, int n_in,
                              void* d_out, int out_size, void* d_ws, size_t ws_size,
                              hipStream_t stream) {
  const float* q  = (const float*)d_in[0];
  const float* k  = (const float*)d_in[1];
  const float* v  = (const float*)d_in[2];
  const float* Wq = (const float*)d_in[3];
  const float* Wk = (const float*)d_in[4];
  const float* Wv = (const float*)d_in[5];
  const float* bq = (const float*)d_in[6];
  const float* bk = (const float*)d_in[7];
  const float* bv = (const float*)d_in[8];
  float* out = (float*)d_out;

  u16* wtq = (u16*)d_ws;                       // 3 x D_*E_ u16
  u16* wtk = wtq + (size_t)D_ * E_;
  u16* wtv = wtk + (size_t)D_ * E_;
  u16* Qp  = wtv + (size_t)D_ * E_;            // 3 x M_*E_ u16
  u16* Kp  = Qp + (size_t)M_ * E_;
  u16* Vp  = Kp + (size_t)M_ * E_;

  prep_w<<<3072, 256, 0, stream>>>(Wq, Wk, Wv, wtq, wtk, wtv);
  proj_gemm<<<1536, 256, 0, stream>>>(
      q, k, v, wtq, wtk, wtv, bq, bk, bv, Qp, Kp, Vp);
  attn_kernel<<<512, 512, 0, stream>>>(Qp, Kp, Vp, out);
}

// Round 23
// 77.898 us; speedup vs baseline: 1.8425x; 1.8425x over previous
//
#include <hip/hip_runtime.h>
#include <hip/hip_bf16.h>
#include <cstdint>

#define B_ 4
#define N_ 2048
#define D_ 512
#define E_ 512
#define H_ 8
#define CH_ 64
#define M_ (B_*N_)   // 8192

typedef __attribute__((ext_vector_type(8))) short bf16x8;
typedef __attribute__((ext_vector_type(4))) float f32x4;
typedef __attribute__((ext_vector_type(16))) float f32x16;
using u16 = unsigned short;
using u32 = unsigned int;

__device__ __forceinline__ u16 f2bf(float f) {
  union { __hip_bfloat16 h; u16 u; } cv;
  cv.h = __float2bfloat16(f);
  return cv.u;
}

__device__ __forceinline__ float fexp2(float x) {
#if __has_builtin(__builtin_amdgcn_exp2f)
  return __builtin_amdgcn_exp2f(x);
#else
  return exp2f(x);
#endif
}

__device__ __forceinline__ void async16(const void* g, void* l) {
  __builtin_amdgcn_global_load_lds(
      (__attribute__((address_space(1))) void*)(g),
      (__attribute__((address_space(3))) void*)(l),
      16, 0, 0);
}

// ---------------- prepass: W^T only (f32 -> bf16 transpose, 1.5MB) ----------------
__global__ void prep_w(const float* __restrict__ Wq, const float* __restrict__ Wk,
                       const float* __restrict__ Wv,
                       u16* __restrict__ tq, u16* __restrict__ tk, u16* __restrict__ tv) {
  int bid = blockIdx.x;
  int t = bid >> 10;                       // 1024 blocks per matrix
  const float* W = (t == 0) ? Wq : (t == 1 ? Wk : Wv);
  u16* T = (t == 0) ? tq : (t == 1 ? tk : tv);
  int idx = ((bid & 1023) << 8) + threadIdx.x;
  int e = idx >> 9, kd = idx & 511;
  T[idx] = f2bf(W[kd * E_ + e]);
}

// ---------------- projection GEMM v3 (round-18/21 proven): f32 A reg-staged, XCD-owner ------
#define GBM 128
#define GBN 64
#define GBK 64

__global__ __launch_bounds__(256) void proj_gemm(
    const float* __restrict__ xq, const float* __restrict__ xk, const float* __restrict__ xv,
    const u16* __restrict__ wtq, const u16* __restrict__ wtk, const u16* __restrict__ wtv,
    const float* __restrict__ bq, const float* __restrict__ bk, const float* __restrict__ bv,
    u16* __restrict__ Qp, u16* __restrict__ Kp, u16* __restrict__ Vp) {
  const int bid = blockIdx.x;
  const int xcd = bid & 7;
  const int t   = bid >> 3;
  const int x8  = t & 7;
  const int gp  = xcd * 24 + (t >> 3);
  const int y   = gp & 63;
  const int z   = gp >> 6;

  const float* X = (z == 0) ? xq : (z == 1 ? xk : xv);
  const u16* WT  = (z == 0) ? wtq : (z == 1 ? wtk : wtv);
  const float* bias = (z == 0) ? bq : (z == 1 ? bk : bv);
  u16* Out = (z == 0) ? Qp : (z == 1 ? Kp : Vp);
  const float scale = (z == 0) ? 0.18033688011112042f : 1.0f;  // 0.125*log2(e)
  const bool vlayout = (z == 2);

  __shared__ __align__(16) u16 As[GBM * GBK];   // bf16, swizzled, 16KB
  __shared__ __align__(16) u16 Bs[GBN * GBK];   // 8KB

  const int tid = threadIdx.x;
  const int l = tid & 63, w = tid >> 6;
  const int wr = w >> 1, wc = w & 1;
  const int m0 = y * GBM;
  const int e0 = x8 * GBN;

  f32x4 acc[4][2] = {};

  for (int ks = 0; ks < D_ / GBK; ++ks) {
    const int k0 = ks * GBK;
#pragma unroll
    for (int i = 0; i < 2; ++i) {
      int o = i * 4096 + tid * 16;
      int row = o >> 7, colb = o & 127;
      int scol = colb ^ ((row & 7) << 4);
      async16((const char*)WT + ((size_t)(e0 + row) * D_ + k0) * 2 + scol, (char*)Bs + o);
    }
    float4 fa[4], fb_[4];
#pragma unroll
    for (int i = 0; i < 4; ++i) {
      int o = i * 4096 + tid * 16;
      int row = o >> 7, colb = o & 127;
      const char* src = (const char*)X + ((size_t)(m0 + row) * D_ + k0) * 4 + colb * 2;
      fa[i]  = *reinterpret_cast<const float4*>(src);
      fb_[i] = *reinterpret_cast<const float4*>(src + 16);
    }
#pragma unroll
    for (int i = 0; i < 4; ++i) {
      int o = i * 4096 + tid * 16;
      int row = o >> 7;
      union { u16 us[8]; bf16x8 v8; } cu;
      cu.us[0] = f2bf(fa[i].x); cu.us[1] = f2bf(fa[i].y);
      cu.us[2] = f2bf(fa[i].z); cu.us[3] = f2bf(fa[i].w);
      cu.us[4] = f2bf(fb_[i].x); cu.us[5] = f2bf(fb_[i].y);
      cu.us[6] = f2bf(fb_[i].z); cu.us[7] = f2bf(fb_[i].w);
      *reinterpret_cast<bf16x8*>((char*)As + (o ^ ((row & 7) << 4))) = cu.v8;
    }
    __syncthreads();
#pragma unroll
    for (int kk = 0; kk < 2; ++kk) {
      bf16x8 af[4], bfr[2];
#pragma unroll
      for (int m = 0; m < 4; ++m) {
        int row = wr * 64 + m * 16 + (l & 15);
        int addr = (row << 7) + kk * 64 + ((l >> 4) << 4);
        addr ^= (row & 7) << 4;
        af[m] = *reinterpret_cast<const bf16x8*>((const char*)As + addr);
      }
#pragma unroll
      for (int n = 0; n < 2; ++n) {
        int row = wc * 32 + n * 16 + (l & 15);
        int addr = (row << 7) + kk * 64 + ((l >> 4) << 4);
        addr ^= (row & 7) << 4;
        bfr[n] = *reinterpret_cast<const bf16x8*>((const char*)Bs + addr);
      }
#pragma unroll
      for (int m = 0; m < 4; ++m)
#pragma unroll
        for (int n = 0; n < 2; ++n)
          acc[m][n] = __builtin_amdgcn_mfma_f32_16x16x32_bf16(af[m], bfr[n], acc[m][n], 0, 0, 0);
    }
    __syncthreads();
  }

#pragma unroll
  for (int m = 0; m < 4; ++m) {
#pragma unroll
    for (int n = 0; n < 2; ++n) {
      int ge = e0 + wc * 32 + n * 16 + (l & 15);
      int h = ge >> 6, c = ge & 63;
      float bv_ = bias[ge];
      int gm0 = m0 + wr * 64 + m * 16 + ((l >> 4) << 2);
      int b = gm0 >> 11, nn0 = gm0 & 2047;
      if (vlayout) {
        short4 sv;
#pragma unroll
        for (int j = 0; j < 4; ++j)
          ((u16*)&sv)[j] = f2bf((acc[m][n][j] + bv_) * scale);
        int np = (((nn0 >> 2) ^ (nn0 >> 3)) & 1) ? (nn0 ^ 12) : nn0;
        *reinterpret_cast<short4*>(
            &Out[(((size_t)b * H_ + h) * CH_ + c) * N_ + np]) = sv;
      } else {
#pragma unroll
        for (int j = 0; j < 4; ++j) {
          u16 oval = f2bf((acc[m][n][j] + bv_) * scale);
          Out[((((size_t)b * H_ + h) * N_ + nn0 + j) << 6) + c] = oval;
        }
      }
    }
  }
}

// ---------------- flash attention v8 (frozen best: conflict-free pair-interleave, KVB=32) ----
#define QBLK 128
#define KVB 32
#define NTH 32   // tiles per half

#define MFMA32(A, Bv, C) __builtin_amdgcn_mfma_f32_32x32x16_bf16((A), (Bv), (C), 0, 0, 0)

__global__ __launch_bounds__(512, 2) void attn_kernel(
    const u16* __restrict__ Qp, const u16* __restrict__ Kp, const u16* __restrict__ Vp,
    float* __restrict__ out) {
  __shared__ __align__(16) u16 Kb[2][2][2048];   // [dbuf][half] 4KB tiles
  __shared__ __align__(16) u16 Vb[2][2][2048];
  __shared__ float shL[4][64];

  const int tid = threadIdx.x;
  const int l = tid & 63, w = tid >> 6;
  const int wsub = w & 3, hf = w >> 2;
  const int qcol = l & 31, hi = l >> 5;

  const int beta = blockIdx.x;
  const int xcd = beta & 7, r = beta >> 3;
  const int bh = xcd * 4 + (r >> 4);
  const int qt = r & 15;

  const u16* Qh = Qp + (size_t)bh * N_ * CH_;
  const u16* Kh = Kp + (size_t)bh * N_ * CH_;
  const u16* Vh = Vp + (size_t)bh * CH_ * N_;
  const int bb = bh >> 3, hh = bh & 7;
  const int qrow = qt * QBLK + wsub * 32 + qcol;

  bf16x8 qf[4];
  {
    const u16* qptr = Qh + (size_t)qrow * CH_;
#pragma unroll
    for (int ks = 0; ks < 4; ++ks)
      qf[ks] = *reinterpret_cast<const bf16x8*>(qptr + ks * 16 + hi * 8);
  }

  f32x16 o0 = {}, o1 = {};
  float lrun = 0.f;

  const int kbase = ((qcol >> 1) << 8) + ((qcol & 1) << 4);
  const int kxor  = (qcol >> 1) & 7;
  const int vbase = ((qcol >> 2) << 8) + ((qcol & 3) << 4);
  const int vxor  = (qcol >> 2) & 3;

  const int st = tid & 255;
  const int tb = hf * (N_ / 2);

  const int so    = st * 16;
  const int kpair = so >> 8;
  const int krow  = (kpair << 1) | ((so >> 4) & 1);
  const int kcol  = ((((so >> 5) & 7) ^ (kpair & 7)) << 4) | (so & 15);
  const int vquad = so >> 8;
  const int vrow  = (vquad << 2) | ((so >> 4) & 3);
  const int vcol  = ((((so >> 6) & 3) ^ (vquad & 3)) << 4) | (so & 15);

#define STAGE(BUF, KV) do {                                                      \
    async16((const char*)Kh + (size_t)((KV) + krow) * 128 + kcol,                \
            (char*)&Kb[BUF][hf][0] + so);                                        \
    async16((const char*)Vh + (size_t)vrow * (N_ * 2) + (KV) * 2 + vcol,         \
            (char*)&Vb[BUF][hf][0] + so);                                        \
  } while (0)

#define TILE(BUF, TL) do {                                                       \
    if ((TL) + 1 < NTH) STAGE((BUF) ^ 1, tb + ((TL) + 1) * KVB);                 \
    f32x16 s0 = {};                                                              \
    __builtin_amdgcn_s_setprio(1);                                               \
    _Pragma("unroll")                                                            \
    for (int ks = 0; ks < 4; ++ks) {                                             \
      int ka = kbase + ((((ks << 1) | hi) ^ kxor) << 5);                         \
      bf16x8 kf = *reinterpret_cast<const bf16x8*>((const char*)&Kb[BUF][hf][0] + ka); \
      s0 = MFMA32(kf, qf[ks], s0);                                               \
    }                                                                            \
    __builtin_amdgcn_s_setprio(0);                                               \
    _Pragma("unroll")                                                            \
    for (int rr = 0; rr < 16; ++rr) s0[rr] = fexp2(s0[rr]);                      \
    {                                                                            \
      float t0 = (s0[0] + s0[1]) + (s0[2] + s0[3]);                              \
      float t1 = (s0[4] + s0[5]) + (s0[6] + s0[7]);                              \
      float t2 = (s0[8] + s0[9]) + (s0[10] + s0[11]);                            \
      float t3 = (s0[12] + s0[13]) + (s0[14] + s0[15]);                          \
      float rsum = (t0 + t1) + (t2 + t3);                                        \
      rsum += __shfl_xor(rsum, 32);                                              \
      lrun += rsum;                                                              \
    }                                                                            \
    __builtin_amdgcn_s_setprio(1);                                               \
    _Pragma("unroll")                                                            \
    for (int ks = 0; ks < 2; ++ks) {                                             \
      union { u16 us[8]; bf16x8 v8; } pu;                                        \
      _Pragma("unroll")                                                          \
      for (int j = 0; j < 8; ++j) pu.us[j] = f2bf(s0[ks * 8 + j]);               \
      int va = vbase + ((((ks << 1) | hi) ^ vxor) << 6);                         \
      bf16x8 v0 = *reinterpret_cast<const bf16x8*>((const char*)&Vb[BUF][hf][0] + va);        \
      bf16x8 v1 = *reinterpret_cast<const bf16x8*>((const char*)&Vb[BUF][hf][0] + va + 2048); \
      o0 = MFMA32(v0, pu.v8, o0);                                                \
      o1 = MFMA32(v1, pu.v8, o1);                                                \
    }                                                                            \
    __builtin_amdgcn_s_setprio(0);                                               \
    __syncthreads();                                                             \
  } while (0)

  STAGE(0, tb);
  __syncthreads();

  for (int tl = 0; tl < NTH; tl += 2) {
    TILE(0, tl);
    TILE(1, tl + 1);
  }

  float* pb = (wsub < 2) ? ((float*)&Kb[0][0][0] + wsub * 2048 + l * 4)
                         : ((float*)&Vb[0][0][0] + (wsub - 2) * 2048 + l * 4);
  if (hf == 1) {
#pragma unroll
    for (int c = 0; c < 4; ++c) {
      float4 s;
      s.x = o0[c * 4 + 0]; s.y = o0[c * 4 + 1];
      s.z = o0[c * 4 + 2]; s.w = o0[c * 4 + 3];
      *reinterpret_cast<float4*>(pb + c * 256) = s;
    }
#pragma unroll
    for (int c = 0; c < 4; ++c) {
      float4 s;
      s.x = o1[c * 4 + 0]; s.y = o1[c * 4 + 1];
      s.z = o1[c * 4 + 2]; s.w = o1[c * 4 + 3];
      *reinterpret_cast<float4*>(pb + (4 + c) * 256) = s;
    }
    shL[wsub][l] = lrun;
  }
  __syncthreads();
  if (hf == 0) {
    float inv = 1.0f / (lrun + shL[wsub][l]);
    const size_t obase = ((size_t)bb * N_ + qrow) * E_ + hh * CH_;
#pragma unroll
    for (int c = 0; c < 4; ++c) {
      float4 p = *reinterpret_cast<const float4*>(pb + c * 256);
      float4 stv;
      stv.x = (o0[c * 4 + 0] + p.x) * inv;
      stv.y = (o0[c * 4 + 1] + p.y) * inv;
      stv.z = (o0[c * 4 + 2] + p.z) * inv;
      stv.w = (o0[c * 4 + 3] + p.w) * inv;
      *reinterpret_cast<float4*>(out + obase + c * 8 + hi * 4) = stv;
    }
#pragma unroll
    for (int c = 0; c < 4; ++c) {
      float4 p = *reinterpret_cast<const float4*>(pb + (4 + c) * 256);
      float4 stv;
      stv.x = (o1[c * 4 + 0] + p.x) * inv;
      stv.y = (o1[c * 4 + 1] + p.y) * inv;
      stv.z = (o1[c * 4 + 2] + p.z) * inv;
      stv.w = (o1[c * 4 + 3] + p.w) * inv;
      *reinterpret_cast<float4*>(out + obase + 32 + c * 8 + hi * 4) = stv;
    }
  }
#undef STAGE
#undef TILE
}

extern "C" void kernel_launch(void* const* d_in, const int* in_sizes, int n_in,
                              void* d_out, int out_size, void* d_ws, size_t ws_size,
                              hipStream_t stream) {
  const float* q  = (const float*)d_in[0];
  const float* k  = (const float*)d_in[1];
  const float* v  = (const float*)d_in[2];
  const float* Wq = (const float*)d_in[3];
  const float* Wk = (const float*)d_in[4];
  const float* Wv = (const float*)d_in[5];
  const float* bq = (const float*)d_in[6];
  const float* bk = (const float*)d_in[7];
  const float* bv = (const float*)d_in[8];
  float* out = (float*)d_out;

  u16* wtq = (u16*)d_ws;                       // 3 x D_*E_ u16
  u16* wtk = wtq + (size_t)D_ * E_;
  u16* wtv = wtk + (size_t)D_ * E_;
  u16* Qp  = wtv + (size_t)D_ * E_;            // 3 x M_*E_ u16
  u16* Kp  = Qp + (size_t)M_ * E_;
  u16* Vp  = Kp + (size_t)M_ * E_;

  prep_w<<<3072, 256, 0, stream>>>(Wq, Wk, Wv, wtq, wtk, wtv);
  proj_gemm<<<1536, 256, 0, stream>>>(
      q, k, v, wtq, wtk, wtv, bq, bk, bv, Qp, Kp, Vp);
  attn_kernel<<<512, 512, 0, stream>>>(Qp, Kp, Vp, out);
}